// Round 1
// 1057.113 us; speedup vs baseline: 1.3217x; 1.3217x over previous
//
#include <hip/hip_runtime.h>
#include <stdint.h>

#define KDIM 1792
#define MDIM 3136
#define MPAD 3328           // 13 * 256 (B padded with zero rows; padded cols masked to BIGV)
#define NROWS 50176         // 16*3136
#define BM 256
#define BN 256
#define BK 64
#define NKT (KDIM / BK)     // 28 K-tiles
#define NTN (MPAD / BN)     // 13 col tiles
#define NTR (NROWS / BM)    // 196 row tiles
#define NSLOT (NTN * 4)     // 52 partial top-3 slots per row (one per 64-col wave strip)
#define BIGV 1e30f

typedef __bf16 bf16;
typedef __attribute__((ext_vector_type(8))) __bf16 bf16x8;
typedef __attribute__((ext_vector_type(4))) float f32x4;

// global_load_lds address-space casts (LDS aperture low 32 bits = LDS offset)
#define AS1(p) ((const __attribute__((address_space(1))) uint32_t*)(uintptr_t)(p))
#define AS3(p) ((__attribute__((address_space(3))) uint32_t*)(uint32_t)(uintptr_t)(p))

__device__ __forceinline__ uint16_t f2bf(float x) {
    union { float f; uint32_t u; } v; v.f = x;
    uint32_t r = (v.u + 0x7fffu + ((v.u >> 16) & 1u)) >> 16;  // RNE
    return (uint16_t)r;
}

// ---- prep 1: phi fp32 -> bf16 + fp32 row sum-of-squares. Wave-per-row, grid-stride. ----
// (Was 50176 one-row blocks -> dispatch-overhead bound. 448 float4 per row = 7*64 exactly.)
__global__ void __launch_bounds__(256) prep_phi(const float* __restrict__ phi,
                                                uint16_t* __restrict__ phiB,
                                                float* __restrict__ rowsq) {
    const int lane = threadIdx.x & 63, w = threadIdx.x >> 6;
    const int step = gridDim.x * 4;
    for (int r = blockIdx.x * 4 + w; r < NROWS; r += step) {
        const float4* src = (const float4*)(phi + (size_t)r * KDIM);
        ushort4* dst = (ushort4*)(phiB + (size_t)r * KDIM);
        float ss = 0.f;
#pragma unroll
        for (int i = 0; i < 7; ++i) {
            float4 v = src[lane + i * 64];
            ss += v.x * v.x + v.y * v.y + v.z * v.z + v.w * v.w;
            ushort4 o;
            o.x = f2bf(v.x); o.y = f2bf(v.y); o.z = f2bf(v.z); o.w = f2bf(v.w);
            dst[lane + i * 64] = o;
        }
#pragma unroll
        for (int off = 32; off > 0; off >>= 1) ss += __shfl_down(ss, off, 64);
        if (lane == 0) rowsq[r] = ss;
    }
}

// ---- prep 2: C_bank [K,M] fp32 -> Bp [MPAD,K] bf16 (transpose), + column sumsq (atomic). ----
__global__ void __launch_bounds__(256) prep_bank(const float* __restrict__ Cb,
                                                 uint16_t* __restrict__ Bp,
                                                 float* __restrict__ colsq) {
    const int m0 = blockIdx.x * 64;   // 49 tiles (3136 = 49*64)
    const int k0 = blockIdx.y * 64;   // 28 tiles
    const int t = threadIdx.x;
    const int ci = t & 63, rg = t >> 6;
    __shared__ float tile[64][65];
    __shared__ float ps[4][64];
    float ss = 0.f;
#pragma unroll
    for (int i = 0; i < 16; ++i) {
        int r = i * 4 + rg;
        float v = Cb[(size_t)(k0 + r) * MDIM + m0 + ci];
        tile[r][ci] = v;
        ss += v * v;
    }
    ps[rg][ci] = ss;
    __syncthreads();
    if (rg == 0) atomicAdd(&colsq[m0 + ci], ps[0][ci] + ps[1][ci] + ps[2][ci] + ps[3][ci]);
#pragma unroll
    for (int i = 0; i < 16; ++i) {
        int mr = i * 4 + rg;
        Bp[(size_t)(m0 + mr) * KDIM + k0 + ci] = f2bf(tile[ci][mr]);
    }
}

// ---- main: 256x256 tile, BK=64, 512 threads (8 waves 2Mx4N), 128 KiB LDS double-buffer,
// 4-phase-per-K-tile schedule with counted vmcnt (T3+T4), setprio around MFMA (T5),
// XOR-swizzled LDS (T2, kept from prev version), fused top-3-of-dist^2 epilogue.
//
// Staging stream: half-tile position p (tile=p>>2, half-id p&3 in order A0,A1,B0,B1).
// Phase (x,q) issues position 4x+q+6 (prologue issues 0..5). Clobber ledger:
//   tile x reads: A in phases 0,1; B in phases 0..2 (all from buf x&1).
//   tile x+2 (same buf) stages issue at (x,2),(x,3),(x+1,0),(x+1,1) -> strictly after
//   the last read of the region under barrier lockstep (A stages after phase1, B-half
//   stages land in opposite buffer or after B reads done). In-flight writes at any
//   read point target the opposite buffer or the disjoint A/B region.
// vmcnt(4) at phase 3 (= 2 half-tiles in flight) guarantees tile x+1 fully staged.
__global__ void __launch_bounds__(512, 2) gemm_topk(const uint16_t* __restrict__ phiB,
                                                    const uint16_t* __restrict__ Bp,
                                                    const float* __restrict__ colsq,
                                                    float* __restrict__ ptop) {
    __shared__ __align__(16) bf16 S[65536];   // 128 KiB: A[2][256][64] | B[2][256][64]

    // bijective XCD swizzle (m204 variant; nwg=2548 not divisible by 8)
    const int nwg = NTR * NTN;
    const int qq = nwg >> 3, rr = nwg & 7;
    const int bid = blockIdx.x;
    const int xcd = bid & 7, lid = bid >> 3;
    const int swz = (xcd < rr ? xcd * (qq + 1) : rr * (qq + 1) + (xcd - rr) * qq) + lid;
    const int tn = swz % NTN, tr = swz / NTN;
    const int rowBase = tr * BM, colBase = tn * BN;

    const int t = threadIdx.x;
    const int lane = t & 63, w = t >> 6;
    const int wr = w >> 2, wc = w & 3;               // wave -> 128x64 output strip
    const int laneM = lane & 15, laneK = lane >> 4;
    const int m7 = laneM & 7;

    // LDS fragment read bases (element offsets; swizzle: k-chunk j stored at slot j^(row&7))
    const uint32_t j0 = (uint32_t)((laneK ^ m7) * 8);
    const uint32_t aRow = (uint32_t)((wr * 128 + laneM) * 64);
    const uint32_t bRow = 32768u + (uint32_t)((wc * 64 + laneM) * 64);
    const uint32_t aB0 = aRow + j0, aB1 = aRow + (j0 ^ 32u);   // ks=0 / ks=1
    const uint32_t bB0 = bRow + j0, bB1 = bRow + (j0 ^ 32u);

    // staging addresses: chunk c = t (+512): row rl=c>>3, lds k-slot jl=c&7, global chunk jl^(rl&7)
    const int rl = t >> 3, jl = t & 7;
    const int gj = jl ^ (rl & 7);
    const uint16_t* gA0 = phiB + (size_t)(rowBase + rl) * KDIM + gj * 8;
    const uint16_t* gB0g = Bp + (size_t)(colBase + rl) * KDIM + gj * 8;
    const uint32_t d0 = (uint32_t)t * 8u;

    f32x4 acc[8][4];
    f32x4 zero = {0.f, 0.f, 0.f, 0.f};
#pragma unroll
    for (int m = 0; m < 8; ++m)
#pragma unroll
        for (int n = 0; n < 4; ++n) acc[m][n] = zero;

#define STAGE(P)                                                                          \
    do {                                                                                  \
        int p_ = (P);                                                                     \
        if (p_ < 4 * NKT) {                                                               \
            int tile_ = p_ >> 2, hh_ = p_ & 3;                                            \
            uint32_t doff_ = ((hh_ & 2) ? 32768u : 0u) + ((tile_ & 1) ? 16384u : 0u)      \
                           + ((hh_ & 1) ? 8192u : 0u) + d0;                               \
            const uint16_t* g_ = ((hh_ & 2) ? gB0g : gA0)                                 \
                               + (size_t)(hh_ & 1) * (128 * KDIM) + tile_ * 64;           \
            __builtin_amdgcn_global_load_lds(AS1(g_), AS3(S + doff_), 16, 0, 0);          \
            __builtin_amdgcn_global_load_lds(AS1(g_ + 64 * KDIM), AS3(S + doff_ + 4096u), \
                                             16, 0, 0);                                   \
        }                                                                                 \
    } while (0)

#define SB __builtin_amdgcn_sched_barrier(0)

    // prologue: tile0 (4 halves) + tile1 A0,A1 -> 12 loads; wait oldest 8 (tile0 done)
#pragma unroll
    for (int p = 0; p < 6; ++p) STAGE(p);
    asm volatile("s_waitcnt vmcnt(4)" ::: "memory");
    __builtin_amdgcn_s_barrier();
    SB;

    for (int x = 0; x < NKT; ++x) {
        const uint32_t bo = (x & 1) ? 16384u : 0u;
        bf16x8 a0[8], a1[8], b0[4], b1[4];

        // ---- phase 0: read A ks0 (8) + B ks0 (4); stage tile x+1 B0; MFMA m0-3 x ks0
#pragma unroll
        for (int m = 0; m < 8; ++m) a0[m] = *(const bf16x8*)(S + (bo + aB0 + m * 1024u));
#pragma unroll
        for (int n = 0; n < 4; ++n) b0[n] = *(const bf16x8*)(S + (bo + bB0 + n * 1024u));
        STAGE(4 * x + 6);
        SB;
        __builtin_amdgcn_s_barrier();
        asm volatile("s_waitcnt lgkmcnt(0)" ::: "memory");
        SB;
        __builtin_amdgcn_s_setprio(1);
#pragma unroll
        for (int m = 0; m < 4; ++m)
#pragma unroll
            for (int n = 0; n < 4; ++n)
                acc[m][n] = __builtin_amdgcn_mfma_f32_16x16x32_bf16(a0[m], b0[n], acc[m][n], 0, 0, 0);
        __builtin_amdgcn_s_setprio(0);
        SB;
        __builtin_amdgcn_s_barrier();
        SB;

        // ---- phase 1: read A ks1 (8); stage tile x+1 B1; MFMA m4-7 x ks0
#pragma unroll
        for (int m = 0; m < 8; ++m) a1[m] = *(const bf16x8*)(S + (bo + aB1 + m * 1024u));
        STAGE(4 * x + 7);
        SB;
        __builtin_amdgcn_s_barrier();
        asm volatile("s_waitcnt lgkmcnt(0)" ::: "memory");
        SB;
        __builtin_amdgcn_s_setprio(1);
#pragma unroll
        for (int m = 4; m < 8; ++m)
#pragma unroll
            for (int n = 0; n < 4; ++n)
                acc[m][n] = __builtin_amdgcn_mfma_f32_16x16x32_bf16(a0[m], b0[n], acc[m][n], 0, 0, 0);
        __builtin_amdgcn_s_setprio(0);
        SB;
        __builtin_amdgcn_s_barrier();
        SB;

        // ---- phase 2: read B ks1 (4); stage tile x+2 A0; MFMA m0-3 x ks1
#pragma unroll
        for (int n = 0; n < 4; ++n) b1[n] = *(const bf16x8*)(S + (bo + bB1 + n * 1024u));
        STAGE(4 * x + 8);
        SB;
        __builtin_amdgcn_s_barrier();
        asm volatile("s_waitcnt lgkmcnt(0)" ::: "memory");
        SB;
        __builtin_amdgcn_s_setprio(1);
#pragma unroll
        for (int m = 0; m < 4; ++m)
#pragma unroll
            for (int n = 0; n < 4; ++n)
                acc[m][n] = __builtin_amdgcn_mfma_f32_16x16x32_bf16(a1[m], b1[n], acc[m][n], 0, 0, 0);
        __builtin_amdgcn_s_setprio(0);
        SB;
        __builtin_amdgcn_s_barrier();
        SB;

        // ---- phase 3: stage tile x+2 A1; counted vmcnt (tile x+1 staged); MFMA m4-7 x ks1
        STAGE(4 * x + 9);
        if (x < NKT - 2) {
            asm volatile("s_waitcnt vmcnt(4)" ::: "memory");
        } else if (x == NKT - 2) {
            asm volatile("s_waitcnt vmcnt(0)" ::: "memory");  // stream exhausted: full drain
        }
        SB;
        __builtin_amdgcn_s_barrier();
        SB;
        __builtin_amdgcn_s_setprio(1);
#pragma unroll
        for (int m = 4; m < 8; ++m)
#pragma unroll
            for (int n = 0; n < 4; ++n)
                acc[m][n] = __builtin_amdgcn_mfma_f32_16x16x32_bf16(a1[m], b1[n], acc[m][n], 0, 0, 0);
        __builtin_amdgcn_s_setprio(0);
        SB;
        __builtin_amdgcn_s_barrier();
        SB;
    }
#undef STAGE
#undef SB

    // Epilogue: v = colsq - 2*dot (rowsq added at merge).
    // C/D layout (m89): col = lane&15, row = (lane>>4)*4 + reg.
    float cq[4];
#pragma unroll
    for (int n = 0; n < 4; ++n) {
        int col = colBase + wc * 64 + n * 16 + laneM;
        cq[n] = (col < MDIM) ? colsq[col] : BIGV;  // mask padding cols
    }
#pragma unroll
    for (int m = 0; m < 8; ++m) {
#pragma unroll
        for (int reg = 0; reg < 4; ++reg) {
            float v0 = fmaf(-2.f, acc[m][0][reg], cq[0]);
            float v1 = fmaf(-2.f, acc[m][1][reg], cq[1]);
            float v2 = fmaf(-2.f, acc[m][2][reg], cq[2]);
            float v3 = fmaf(-2.f, acc[m][3][reg], cq[3]);
            // sort4, keep 3 smallest
            float lo01 = fminf(v0, v1), hi01 = fmaxf(v0, v1);
            float lo23 = fminf(v2, v3), hi23 = fmaxf(v2, v3);
            float s0 = fminf(lo01, lo23);
            float mid = fmaxf(lo01, lo23), bb = fminf(hi01, hi23);
            float s1 = fminf(mid, bb), s2 = fmaxf(mid, bb);
            // butterfly merge across the 16 lanes (laneM) sharing this row group
#pragma unroll
            for (int msk = 1; msk <= 8; msk <<= 1) {
                float b0_ = __shfl_xor(s0, msk, 64);
                float b1_ = __shfl_xor(s1, msk, 64);
                float b2_ = __shfl_xor(s2, msk, 64);
                float mn0 = fminf(s0, b0_), mx0 = fmaxf(s0, b0_);
                float mn1 = fminf(s1, b1_), mx1 = fmaxf(s1, b1_);
                float mn2 = fminf(s2, b2_);
                s0 = mn0;
                float n1 = fminf(mx0, mn1);
                s2 = fminf(fmaxf(mx0, mn1), fminf(mx1, mn2));
                s1 = n1;
            }
            if (laneM == 0) {
                int row = rowBase + wr * 128 + m * 16 + laneK * 4 + reg;
                float* o = ptop + ((size_t)(tn * 4 + wc) * NROWS + row) * 3;
                o[0] = s0; o[1] = s1; o[2] = s2;
            }
        }
    }
}

// ---- merge 52 partial top-3 per row -> softmin score ----
__global__ void __launch_bounds__(256) merge_score(const float* __restrict__ ptop,
                                                   const float* __restrict__ rowsq,
                                                   float* __restrict__ out) {
    int r = blockIdx.x * 256 + threadIdx.x;
    if (r >= NROWS) return;
    float t0 = BIGV, t1 = BIGV, t2 = BIGV;
    for (int s = 0; s < NSLOT; ++s) {
        const float* p = ptop + ((size_t)s * NROWS + r) * 3;
#pragma unroll
        for (int j = 0; j < 3; ++j) {
            float x = p[j];
            float n0 = fminf(t0, x);
            float n1 = fminf(t1, fmaxf(t0, x));
            float n2 = fminf(t2, fmaxf(t1, x));
            t0 = n0; t1 = n1; t2 = n2;
        }
    }
    float rq = rowsq[r];
    float d0 = sqrtf(fmaxf(rq + t0, 0.f));
    float d1 = sqrtf(fmaxf(rq + t1, 0.f));
    float d2 = sqrtf(fmaxf(rq + t2, 0.f));
    float w0 = 1.f / (1.f + __expf(d0 - d1) + __expf(d0 - d2));
    out[r] = w0 * d0;
}

extern "C" void kernel_launch(void* const* d_in, const int* in_sizes, int n_in,
                              void* d_out, int out_size, void* d_ws, size_t ws_size,
                              hipStream_t stream) {
    const float* phi = (const float*)d_in[0];   // [16,3136,1792] fp32
    const float* Cb  = (const float*)d_in[1];   // [1792,3136] fp32
    float* out = (float*)d_out;                 // [16,3136,1] fp32

    char* ws = (char*)d_ws;
    size_t o = 0;
    uint16_t* phiB = (uint16_t*)(ws + o); o += (size_t)NROWS * KDIM * 2;   // 179.8 MB
    uint16_t* Bpw  = (uint16_t*)(ws + o); o += (size_t)MPAD * KDIM * 2;    // 11.9 MB
    float* rowsq   = (float*)(ws + o);    o += (size_t)NROWS * 4;
    float* colsq   = (float*)(ws + o);    o += (size_t)MPAD * 4;
    float* ptop    = (float*)(ws + o);    o += (size_t)NSLOT * NROWS * 3 * 4; // 31.3 MB

    hipMemsetAsync(Bpw, 0, (size_t)MPAD * KDIM * 2, stream);   // zero padding rows 3136..3327
    hipMemsetAsync(colsq, 0, (size_t)MPAD * 4, stream);        // atomic accumulation base
    prep_phi<<<2048, 256, 0, stream>>>(phi, phiB, rowsq);
    prep_bank<<<dim3(MDIM / 64, KDIM / 64), 256, 0, stream>>>(Cb, Bpw, colsq);
    gemm_topk<<<NTR * NTN, 512, 0, stream>>>(phiB, Bpw, colsq, ptop);
    merge_score<<<(NROWS + 255) / 256, 256, 0, stream>>>(ptop, rowsq, out);
}